// Round 6
// baseline (8544.295 us; speedup 1.0000x reference)
//
#include <hip/hip_runtime.h>
#include <math.h>

// Problem dims
#define TT 128
#define BB 512
#define EE 100
#define HH 256
#define G4 1024       // 4*H
#define NTAG 20
#define PWSZ 364544   // 356*1024
#define QSZ  25600    // 256*100 (also 100*256 for R)

__device__ __forceinline__ float sigm(float x) { return 1.0f / (1.0f + expf(-x)); }

// ---------------------------------------------------------------------------
// prep5: build 8 per-XCD copies of packed weights PW[k][n] (k 0..99 = Wih^T,
// 100..355 = Whh^T), Q[k][e], R[k][j]; bias bP[n] = bih+bhh (single copy).
// ---------------------------------------------------------------------------
__global__ void prep5(const float* __restrict__ Wih, const float* __restrict__ Whh,
                      const float* __restrict__ bih, const float* __restrict__ bhh,
                      const float* __restrict__ Q, const float* __restrict__ Rm,
                      float* __restrict__ PWx, float* __restrict__ Qx,
                      float* __restrict__ Rx, float* __restrict__ bP)
{
    int idx = blockIdx.x * blockDim.x + threadIdx.x;
    if (idx < PWSZ) {
        int k = idx >> 10, n = idx & 1023;
        float v = (k < EE) ? Wih[n * EE + k] : Whh[n * HH + (k - EE)];
        #pragma unroll
        for (int c = 0; c < 8; ++c) PWx[c * PWSZ + idx] = v;
    } else if (idx < PWSZ + QSZ) {
        int i = idx - PWSZ; float v = Q[i];
        #pragma unroll
        for (int c = 0; c < 8; ++c) Qx[c * QSZ + i] = v;
    } else if (idx < PWSZ + 2 * QSZ) {
        int i = idx - (PWSZ + QSZ); float v = Rm[i];
        #pragma unroll
        for (int c = 0; c < 8; ++c) Rx[c * QSZ + i] = v;
    } else if (idx < PWSZ + 2 * QSZ + G4) {
        int n = idx - (PWSZ + 2 * QSZ);
        bP[n] = bih[n] + bhh[n];
    }
}

// ---- software-pipeline slot macros -----------------------------------------
// Pasted digit-suffixed names are ALWAYS parenthesized before member access.
// P1: 1 row/thread, dot over K=256 (h_prev[r] . Q[:,e]), depth 6
#define P1L(S, kk) { const int kc_ = ((kk) <= 252) ? (kk) : 252;            \
    const float* qp_ = Qd + kc_ * EE + e;                                    \
    q##S##0 = qp_[0]; q##S##1 = qp_[EE]; q##S##2 = qp_[2*EE]; q##S##3 = qp_[3*EE]; \
    H##S = *(const float4*)(sH + r1 * HH + kc_); }
#define P1F(S) { a0 += (H##S).x*(q##S##0) + (H##S).y*(q##S##1) + (H##S).z*(q##S##2) + (H##S).w*(q##S##3); }

// P2: 2 rows/thread, dot over K=100 (xm[r] . R[:,j]), depth 4
#define P2L(S, kk) { const int kc_ = ((kk) <= 96) ? (kk) : 96;              \
    const float* rp_ = Rd + kc_ * HH + j2;                                   \
    w##S##0 = rp_[0]; w##S##1 = rp_[HH]; w##S##2 = rp_[2*HH]; w##S##3 = rp_[3*HH]; \
    X##S##0 = *(const float4*)(sA + rg2 * 356 + kc_);                        \
    X##S##1 = *(const float4*)(sA + (rg2 + 1) * 356 + kc_); }
#define P2F(S) { \
    s0 += (X##S##0).x*(w##S##0) + (X##S##0).y*(w##S##1) + (X##S##0).z*(w##S##2) + (X##S##0).w*(w##S##3); \
    s1 += (X##S##1).x*(w##S##0) + (X##S##1).y*(w##S##1) + (X##S##1).z*(w##S##2) + (X##S##1).w*(w##S##3); }

// P3: 2 cols x 4 rows per thread, merged K=356 over sA=[xm|hm], depth 6
#define P3L(S, kk) { const int kc_ = ((kk) <= 352) ? (kk) : 352;            \
    const float* wp_ = PW + kc_ * G4 + n0;                                   \
    W##S##0 = *(const float2*)(wp_);        W##S##1 = *(const float2*)(wp_ + G4); \
    W##S##2 = *(const float2*)(wp_ + 2*G4); W##S##3 = *(const float2*)(wp_ + 3*G4); \
    const float* xp_ = sA + kc_;                                             \
    X##S##0 = *(const float4*)(xp_);        X##S##1 = *(const float4*)(xp_ + 356); \
    X##S##2 = *(const float4*)(xp_ + 712);  X##S##3 = *(const float4*)(xp_ + 1068); }
#define P3F(S) {                                                             \
    a00 += (X##S##0).x*(W##S##0).x + (X##S##0).y*(W##S##1).x + (X##S##0).z*(W##S##2).x + (X##S##0).w*(W##S##3).x; \
    a01 += (X##S##0).x*(W##S##0).y + (X##S##0).y*(W##S##1).y + (X##S##0).z*(W##S##2).y + (X##S##0).w*(W##S##3).y; \
    a10 += (X##S##1).x*(W##S##0).x + (X##S##1).y*(W##S##1).x + (X##S##1).z*(W##S##2).x + (X##S##1).w*(W##S##3).x; \
    a11 += (X##S##1).x*(W##S##0).y + (X##S##1).y*(W##S##1).y + (X##S##1).z*(W##S##2).y + (X##S##1).w*(W##S##3).y; \
    a20 += (X##S##2).x*(W##S##0).x + (X##S##2).y*(W##S##1).x + (X##S##2).z*(W##S##2).x + (X##S##2).w*(W##S##3).x; \
    a21 += (X##S##2).x*(W##S##0).y + (X##S##2).y*(W##S##1).y + (X##S##2).z*(W##S##2).y + (X##S##2).w*(W##S##3).y; \
    a30 += (X##S##3).x*(W##S##0).x + (X##S##3).y*(W##S##1).x + (X##S##3).z*(W##S##2).x + (X##S##3).w*(W##S##3).x; \
    a31 += (X##S##3).x*(W##S##0).y + (X##S##3).y*(W##S##1).y + (X##S##3).z*(W##S##2).y + (X##S##3).w*(W##S##3).y; }

// ---------------------------------------------------------------------------
// Main recurrence. 256 fully-independent blocks (128 chunks x 2 dirs) = one
// per CU, 512 threads, 4 batch rows, all 1024 gate cols. (C,R)=(2,4): each
// weight float2 feeds 4 rows -> PW read exactly once per block-step.
// Per-XCD weight copies (bid&7) keep the 1.46 MB stream L2-resident.
// ---------------------------------------------------------------------------
__global__ __launch_bounds__(512, 1) void lstm5(
    const int* __restrict__ words, const float* __restrict__ embed,
    const float* __restrict__ Qxf, const float* __restrict__ Rxf,
    const float* __restrict__ PWxf, const float* __restrict__ bPf,
    const float* __restrict__ Qxb, const float* __restrict__ Rxb,
    const float* __restrict__ PWxb, const float* __restrict__ bPb,
    float* hfbuf, float* hbbuf)
{
    const int bid = blockIdx.x;
    const int dir = bid & 1;          // even XCDs: fwd, odd: bwd (round-robin)
    const int xcd = bid & 7;          // per-XCD weight copy index
    const int cb  = bid >> 1;         // 0..127
    const int b0  = cb * 4;
    const int tid = threadIdx.x;

    const float* Qd = (dir ? Qxb : Qxf) + xcd * QSZ;
    const float* Rd = (dir ? Rxb : Rxf) + xcd * QSZ;
    const float* PW = (dir ? PWxb : PWxf) + (size_t)xcd * PWSZ;
    const float* bP = dir ? bPb : bPf;
    float* hout = dir ? hbbuf : hfbuf;

    __shared__ alignas(16) float sA[4 * 356];    // packed [xm(100)|hm(256)] per row
    __shared__ alignas(16) float sH[4 * HH];     // h_prev rows
    __shared__ alignas(16) float sG[4 * G4];     // gate pre-activations (16 KB)

    // phase-1 ids: 1 row x 1 e-col
    const int e  = tid & 127;
    const int r1 = tid >> 7;                     // 0..3
    // phase-2 ids: 2 rows x 1 j-col
    const int j2  = tid & 255;
    const int rg2 = (tid >> 8) * 2;
    // phase-3 ids: 4 rows x 2 cols
    const int n0 = tid * 2;
    // phase-4 ids: 2 rows x 1 col; cell state in registers
    const int j4  = tid & 255;
    const int r4a = (tid >> 8) * 2, r4b = r4a + 1;
    float c0 = 0.f, c1 = 0.f;

    const float2 bv = *(const float2*)(bP + n0);   // hoisted bias

    for (int s = 0; s < TT; ++s) {
        const int t = dir ? (TT - 1 - s) : s;

        // ---- phase 1: xm[r][e] = 2*sig(h_prev[r] . Q[:,e]) * x_t[r][e] ----
        if (e < EE) {
            const int w = words[(b0 + r1) * TT + t];
            const float x = __builtin_nontemporal_load(&embed[(size_t)w * EE + e]);
            if (s == 0) {                 // h=0 -> 2*sig(0)=1 -> xm=x
                sA[r1 * 356 + e] = x;
            } else {
                float a0 = 0.f;
                float qA0,qA1,qA2,qA3,qB0,qB1,qB2,qB3,qC0,qC1,qC2,qC3;
                float qD0,qD1,qD2,qD3,qE0,qE1,qE2,qE3,qF0,qF1,qF2,qF3;
                float4 HA,HB,HC,HD,HE,HF;
                P1L(A,0); P1L(B,4); P1L(C,8); P1L(D,12); P1L(E,16); P1L(F,20);
                for (int kb = 0; kb <= 216; kb += 24) {
                    P1F(A); P1L(A, kb+24); P1F(B); P1L(B, kb+28);
                    P1F(C); P1L(C, kb+32); P1F(D); P1L(D, kb+36);
                    P1F(E); P1L(E, kb+40); P1F(F); P1L(F, kb+44);
                }
                P1F(A); P1F(B); P1F(C); P1F(D);   // k = 240,244,248,252
                sA[r1 * 356 + e] = 2.f * sigm(a0) * x;
            }
        }
        __syncthreads();

        // ---- phase 2: hm[r][j] = 2*sig(xm[r] . R[:,j]) * h_prev[r][j] ----
        if (s == 0) {
            sA[rg2 * 356 + 100 + j2] = 0.f;
            sA[(rg2 + 1) * 356 + 100 + j2] = 0.f;
        } else {
            float s0 = 0.f, s1 = 0.f;
            float wA0,wA1,wA2,wA3,wB0,wB1,wB2,wB3,wC0,wC1,wC2,wC3,wD0,wD1,wD2,wD3;
            float4 XA0,XA1,XB0,XB1,XC0,XC1,XD0,XD1;
            P2L(A,0); P2L(B,4); P2L(C,8); P2L(D,12);
            for (int kb = 0; kb <= 80; kb += 16) {
                P2F(A); P2L(A, kb+16); P2F(B); P2L(B, kb+20);
                P2F(C); P2L(C, kb+24); P2F(D); P2L(D, kb+28);
            }
            P2F(A);                               // k = 96
            sA[rg2 * 356 + 100 + j2]       = 2.f * sigm(s0) * sH[rg2 * HH + j2];
            sA[(rg2 + 1) * 356 + 100 + j2] = 2.f * sigm(s1) * sH[(rg2 + 1) * HH + j2];
        }
        __syncthreads();

        // ---- phase 3: G = [xm|hm] @ PW + bias  (2 cols x 4 rows / thread) --
        {
            float a00=bv.x,a01=bv.y,a10=bv.x,a11=bv.y;
            float a20=bv.x,a21=bv.y,a30=bv.x,a31=bv.y;
            float2 WA0,WA1,WA2,WA3,WB0,WB1,WB2,WB3,WC0,WC1,WC2,WC3;
            float2 WD0,WD1,WD2,WD3,WE0,WE1,WE2,WE3,WF0,WF1,WF2,WF3;
            float4 XA0,XA1,XA2,XA3,XB0,XB1,XB2,XB3,XC0,XC1,XC2,XC3;
            float4 XD0,XD1,XD2,XD3,XE0,XE1,XE2,XE3,XF0,XF1,XF2,XF3;
            P3L(A,0); P3L(B,4); P3L(C,8); P3L(D,12); P3L(E,16); P3L(F,20);
            for (int kb = 0; kb <= 312; kb += 24) {   // 14 iterations
                P3F(A); P3L(A, kb+24); P3F(B); P3L(B, kb+28);
                P3F(C); P3L(C, kb+32); P3F(D); P3L(D, kb+36);
                P3F(E); P3L(E, kb+40); P3F(F); P3L(F, kb+44);
            }
            P3F(A); P3F(B); P3F(C); P3F(D); P3F(E);   // chunks 84..88
            *(float2*)(sG + 0 * G4 + n0) = make_float2(a00, a01);
            *(float2*)(sG + 1 * G4 + n0) = make_float2(a10, a11);
            *(float2*)(sG + 2 * G4 + n0) = make_float2(a20, a21);
            *(float2*)(sG + 3 * G4 + n0) = make_float2(a30, a31);
        }
        __syncthreads();

        // ---- phase 4: cell update; h -> sH (LDS) + nt-store to hout[t] ----
        {
            const float gi0 = sG[r4a*G4 + j4],       gi1 = sG[r4b*G4 + j4];
            const float gf0 = sG[r4a*G4 + 256 + j4], gf1 = sG[r4b*G4 + 256 + j4];
            const float gg0 = sG[r4a*G4 + 512 + j4], gg1 = sG[r4b*G4 + 512 + j4];
            const float go0 = sG[r4a*G4 + 768 + j4], go1 = sG[r4b*G4 + 768 + j4];
            c0 = sigm(gf0) * c0 + sigm(gi0) * tanhf(gg0);
            c1 = sigm(gf1) * c1 + sigm(gi1) * tanhf(gg1);
            const float h0 = sigm(go0) * tanhf(c0);
            const float h1 = sigm(go1) * tanhf(c1);
            sH[r4a * HH + j4] = h0;
            sH[r4b * HH + j4] = h1;
            __builtin_nontemporal_store(h0, &hout[((size_t)t * BB + b0 + r4a) * HH + j4]);
            __builtin_nontemporal_store(h1, &hout[((size_t)t * BB + b0 + r4b) * HH + j4]);
        }
        __syncthreads();
    }
}

// ---------------------------------------------------------------------------
// logits = [hf|hb] @ Wt^T + bt ; argmax (first index on ties) -> out[b][t]
// ---------------------------------------------------------------------------
__global__ __launch_bounds__(256) void logits_kernel(
    const float* __restrict__ hf, const float* __restrict__ hb,
    const float* __restrict__ Wt, const float* __restrict__ bt,
    int* __restrict__ out)
{
    __shared__ float sW[NTAG][2 * HH];
    __shared__ float sb[NTAG];
    const int tid = threadIdx.x;
    for (int i = tid; i < NTAG * 2 * HH; i += 256) (&sW[0][0])[i] = Wt[i];
    if (tid < NTAG) sb[tid] = bt[tid];
    __syncthreads();

    const int pos = blockIdx.x * 256 + tid;
    const int b  = pos & 511;
    const int t0 = pos >> 9;
    const int t1 = t0 + 64;

    float acc0[NTAG], acc1[NTAG];
    #pragma unroll
    for (int n = 0; n < NTAG; ++n) { acc0[n] = sb[n]; acc1[n] = sb[n]; }

    const float* f0 = hf + ((size_t)t0 * BB + b) * HH;
    const float* f1 = hf + ((size_t)t1 * BB + b) * HH;
    for (int k = 0; k < HH; k += 4) {
        const float4 a0 = *(const float4*)(f0 + k);
        const float4 a1 = *(const float4*)(f1 + k);
        #pragma unroll
        for (int n = 0; n < NTAG; ++n) {
            const float4 w = *(const float4*)&sW[n][k];
            acc0[n] += a0.x * w.x + a0.y * w.y + a0.z * w.z + a0.w * w.w;
            acc1[n] += a1.x * w.x + a1.y * w.y + a1.z * w.z + a1.w * w.w;
        }
    }
    const float* g0 = hb + ((size_t)t0 * BB + b) * HH;
    const float* g1 = hb + ((size_t)t1 * BB + b) * HH;
    for (int k = 0; k < HH; k += 4) {
        const float4 a0 = *(const float4*)(g0 + k);
        const float4 a1 = *(const float4*)(g1 + k);
        #pragma unroll
        for (int n = 0; n < NTAG; ++n) {
            const float4 w = *(const float4*)&sW[n][HH + k];
            acc0[n] += a0.x * w.x + a0.y * w.y + a0.z * w.z + a0.w * w.w;
            acc1[n] += a1.x * w.x + a1.y * w.y + a1.z * w.z + a1.w * w.w;
        }
    }

    float b0v = acc0[0]; int i0 = 0;
    float b1v = acc1[0]; int i1 = 0;
    #pragma unroll
    for (int n = 1; n < NTAG; ++n) {
        if (acc0[n] > b0v) { b0v = acc0[n]; i0 = n; }
        if (acc1[n] > b1v) { b1v = acc1[n]; i1 = n; }
    }
    out[b * TT + t0] = i0;
    out[b * TT + t1] = i1;
}

// ---------------------------------------------------------------------------
extern "C" void kernel_launch(void* const* d_in, const int* in_sizes, int n_in,
                              void* d_out, int out_size, void* d_ws, size_t ws_size,
                              hipStream_t stream)
{
    (void)in_sizes; (void)n_in; (void)out_size; (void)ws_size;

    const int*   words = (const int*)  d_in[0];
    const float* embd  = (const float*)d_in[5];
    const float* Wih_f = (const float*)d_in[6];
    const float* Whh_f = (const float*)d_in[7];
    const float* bih_f = (const float*)d_in[8];
    const float* bhh_f = (const float*)d_in[9];
    const float* Q_f   = (const float*)d_in[10];
    const float* R_f   = (const float*)d_in[11];
    const float* Wih_b = (const float*)d_in[12];
    const float* Whh_b = (const float*)d_in[13];
    const float* bih_b = (const float*)d_in[14];
    const float* bhh_b = (const float*)d_in[15];
    const float* Q_b   = (const float*)d_in[16];
    const float* R_b   = (const float*)d_in[17];
    const float* Wt    = (const float*)d_in[18];
    const float* bt    = (const float*)d_in[19];
    int* out = (int*)d_out;

    // workspace layout (floats), total ~161 MB
    float* ws    = (float*)d_ws;
    float* PWx_f = ws;                        // 8*364544
    float* Qx_f  = PWx_f + 8 * PWSZ;          // 8*25600
    float* Rx_f  = Qx_f + 8 * QSZ;            // 8*25600
    float* bP_f  = Rx_f + 8 * QSZ;            // 1024
    float* PWx_b = bP_f + G4;
    float* Qx_b  = PWx_b + 8 * PWSZ;
    float* Rx_b  = Qx_b + 8 * QSZ;
    float* bP_b  = Rx_b + 8 * QSZ;
    float* hf    = bP_b + G4;                 // 16777216
    float* hb    = hf + (size_t)TT * BB * HH; // 16777216

    const int prep_grid = (PWSZ + 2 * QSZ + G4 + 255) / 256;
    prep5<<<prep_grid, 256, 0, stream>>>(Wih_f, Whh_f, bih_f, bhh_f, Q_f, R_f,
                                         PWx_f, Qx_f, Rx_f, bP_f);
    prep5<<<prep_grid, 256, 0, stream>>>(Wih_b, Whh_b, bih_b, bhh_b, Q_b, R_b,
                                         PWx_b, Qx_b, Rx_b, bP_b);
    lstm5<<<256, 512, 0, stream>>>(words, embd, Qx_f, Rx_f, PWx_f, bP_f,
                                   Qx_b, Rx_b, PWx_b, bP_b, hf, hb);
    logits_kernel<<<128, 256, 0, stream>>>(hf, hb, Wt, bt, out);
}

// Round 10
// 3995.687 us; speedup vs baseline: 2.1384x; 2.1384x over previous
//
#include <hip/hip_runtime.h>
#include <math.h>

// Problem dims
#define TT 128
#define BB 512
#define EE 100
#define HH 256
#define G4 1024       // 4*H
#define NTAG 20
#define KP 368        // padded K (356 -> 368, zeros in PW)
#define PWPSZ (KP * G4)       // 376832
#define QPSZ  25600           // 64 kq * 400
#define RPSZ  28672           // 28 kq * 1024 (kq 25..27 zero-padded)

__device__ __forceinline__ float sigm(float x) { return 1.0f / (1.0f + expf(-x)); }

// ---------------------------------------------------------------------------
// prep6 (one direction): PWp[k][n] packed weights k<100 = Wih^T, 100..355 =
// Whh^T, 356..367 = 0. QP[kq][e][kk] = Q[kq*4+kk][e] (k-quad packed).
// RP[kq][j][kk] = R[kq*4+kk][j], zero for k >= 100. bP[n] = bih[n]+bhh[n].
// ---------------------------------------------------------------------------
__global__ void prep6(const float* __restrict__ Wih, const float* __restrict__ Whh,
                      const float* __restrict__ bih, const float* __restrict__ bhh,
                      const float* __restrict__ Q, const float* __restrict__ R,
                      float* __restrict__ PWp, float* __restrict__ QP,
                      float* __restrict__ RP, float* __restrict__ bP)
{
    int idx = blockIdx.x * blockDim.x + threadIdx.x;
    if (idx < PWPSZ) {
        int k = idx >> 10, n = idx & 1023;
        PWp[idx] = (k < EE) ? Wih[n * EE + k]
                 : (k < EE + HH) ? Whh[n * HH + (k - EE)] : 0.f;
    } else if (idx < PWPSZ + QPSZ) {
        int i = idx - PWPSZ;
        int kq = i / 400, rem = i - kq * 400;
        int e = rem >> 2, kk = rem & 3;
        QP[i] = Q[(kq * 4 + kk) * EE + e];
    } else if (idx < PWPSZ + QPSZ + RPSZ) {
        int i = idx - (PWPSZ + QPSZ);
        int kq = i >> 10, rem = i & 1023;
        int j = rem >> 2, kk = rem & 3;
        int k = kq * 4 + kk;
        RP[i] = (k < EE) ? R[k * HH + j] : 0.f;
    } else if (idx < PWPSZ + QPSZ + RPSZ + G4) {
        int n = idx - (PWPSZ + QPSZ + RPSZ);
        bP[n] = bih[n] + bhh[n];
    }
}

// ---- software-pipeline slot macros -----------------------------------------
// Pasted digit-suffixed names are ALWAYS parenthesized before member access.
// P1: 1 row/thread, K=256 as 64 k-quads; quad-dot per chunk. depth 4, no clamp.
#define P1L(S, kq) { \
    q##S = *(const float4*)(QP + (kq) * 400 + e * 4); \
    h##S = *(const float4*)(sH + r1 * HH + (kq) * 4); }
#define P1F(S) { a0 += (h##S).x*(q##S).x + (h##S).y*(q##S).y + (h##S).z*(q##S).z + (h##S).w*(q##S).w; }

// P2: 2 rows/thread, K as 28 k-quads (25 real + 3 zero-weight). depth 4, no clamp.
#define P2L(S, kq) { \
    r##S = *(const float4*)(RP + (kq) * 1024 + j2 * 4); \
    X##S##0 = *(const float4*)(sA + r20 * KP + (kq) * 4); \
    X##S##1 = *(const float4*)(sA + r21 * KP + (kq) * 4); }
#define P2F(S) { \
    s0 += (X##S##0).x*(r##S).x + (X##S##0).y*(r##S).y + (X##S##0).z*(r##S).z + (X##S##0).w*(r##S).w; \
    s1 += (X##S##1).x*(r##S).x + (X##S##1).y*(r##S).y + (X##S##1).z*(r##S).z + (X##S##1).w*(r##S).w; }

// P3: 4 cols x 2 rows/thread, merged K=368 (4-k chunks); clamp at k=364. depth 4.
#define P3L(S, kk) { const int kc_ = ((kk) <= 364) ? (kk) : 364; \
    const float* wp_ = PW + (size_t)kc_ * G4 + n0; \
    W##S##0 = *(const float4*)(wp_);        W##S##1 = *(const float4*)(wp_ + G4); \
    W##S##2 = *(const float4*)(wp_ + 2*G4); W##S##3 = *(const float4*)(wp_ + 3*G4); \
    const float* xp_ = sA + rg3 * KP + kc_; \
    X##S##0 = *(const float4*)(xp_);        X##S##1 = *(const float4*)(xp_ + KP); }
#define P3F(S) { \
    a00 += (X##S##0).x*(W##S##0).x + (X##S##0).y*(W##S##1).x + (X##S##0).z*(W##S##2).x + (X##S##0).w*(W##S##3).x; \
    a01 += (X##S##0).x*(W##S##0).y + (X##S##0).y*(W##S##1).y + (X##S##0).z*(W##S##2).y + (X##S##0).w*(W##S##3).y; \
    a02 += (X##S##0).x*(W##S##0).z + (X##S##0).y*(W##S##1).z + (X##S##0).z*(W##S##2).z + (X##S##0).w*(W##S##3).z; \
    a03 += (X##S##0).x*(W##S##0).w + (X##S##0).y*(W##S##1).w + (X##S##0).z*(W##S##2).w + (X##S##0).w*(W##S##3).w; \
    a10 += (X##S##1).x*(W##S##0).x + (X##S##1).y*(W##S##1).x + (X##S##1).z*(W##S##2).x + (X##S##1).w*(W##S##3).x; \
    a11 += (X##S##1).x*(W##S##0).y + (X##S##1).y*(W##S##1).y + (X##S##1).z*(W##S##2).y + (X##S##1).w*(W##S##3).y; \
    a12 += (X##S##1).x*(W##S##0).z + (X##S##1).y*(W##S##1).z + (X##S##1).z*(W##S##2).z + (X##S##1).w*(W##S##3).z; \
    a13 += (X##S##1).x*(W##S##0).w + (X##S##1).y*(W##S##1).w + (X##S##1).z*(W##S##2).w + (X##S##1).w*(W##S##3).w; }

// ---------------------------------------------------------------------------
// Main recurrence. 256 fully-independent blocks (128 chunks x 2 dirs), 512
// threads, 4 batch rows, all 1024 gate cols. LDS-pipe-lean layout:
// (C,R)=(4,2) in phase 3 (1 broadcast b128 per 16 FMA), k-quad-packed Q/R
// (1 coalesced b128 per chunk in p1/p2).
// ---------------------------------------------------------------------------
__global__ __launch_bounds__(512, 1) void lstm6(
    const int* __restrict__ words, const float* __restrict__ embed,
    const float* __restrict__ QPf, const float* __restrict__ RPf,
    const float* __restrict__ PWf, const float* __restrict__ bPf,
    const float* __restrict__ QPb, const float* __restrict__ RPb,
    const float* __restrict__ PWb, const float* __restrict__ bPb,
    float* hfbuf, float* hbbuf)
{
    const int bid = blockIdx.x;
    const int dir = bid & 1;
    const int cb  = bid >> 1;         // 0..127
    const int b0  = cb * 4;
    const int tid = threadIdx.x;

    const float* QP = dir ? QPb : QPf;
    const float* RP = dir ? RPb : RPf;
    const float* PW = dir ? PWb : PWf;
    const float* bP = dir ? bPb : bPf;
    float* hout = dir ? hbbuf : hfbuf;

    __shared__ alignas(16) float sA[4 * KP];     // [xm(100)|hm(256)|pad12] per row
    __shared__ alignas(16) float sH[4 * HH];     // h_prev rows
    __shared__ alignas(16) float sG[4 * G4];     // gate pre-activations (16 KB)
    __shared__ int sWords[4 * TT];               // word ids, preloaded

    // phase-1 ids: 1 row x 1 e-col
    const int e  = tid & 127;
    const int r1 = tid >> 7;                     // 0..3
    // phase-2 ids: 2 rows x 1 j-col
    const int j2  = tid & 255;
    const int r20 = (tid >> 8) * 2, r21 = r20 + 1;
    // phase-3 ids: 2 rows x 4 cols
    const int n0  = (tid & 255) * 4;
    const int rg3 = (tid >> 8) * 2;
    // phase-4 ids: 2 rows x 1 col; cell state in registers
    const int j4  = tid & 255;
    const int r4a = (tid >> 8) * 2, r4b = r4a + 1;
    float c0 = 0.f, c1 = 0.f;

    const float4 bv = *(const float4*)(bP + n0);   // hoisted bias

    // preload word ids; zero the 12-float K-pad of each sA row (read by P3
    // against zero weights -- must not contain NaN bit patterns)
    sWords[tid & 511] = words[(b0 + (tid >> 7)) * TT + (tid & 127)];
    if (tid < 48) {
        const int r = tid / 12, p = tid - r * 12;
        sA[r * KP + 356 + p] = 0.f;
    }
    __syncthreads();

    for (int s = 0; s < TT; ++s) {
        const int t = dir ? (TT - 1 - s) : s;

        // ---- phase 1: xm[r][e] = 2*sig(h_prev[r] . Q[:,e]) * x_t[r][e] ----
        if (e < EE) {
            const int w = sWords[r1 * TT + t];
            const float x = __builtin_nontemporal_load(&embed[(size_t)w * EE + e]);
            if (s == 0) {                 // h=0 -> 2*sig(0)=1 -> xm=x
                sA[r1 * KP + e] = x;
            } else {
                float a0 = 0.f;
                float4 qA, qB, qC, qD, hA, hB, hC, hD;
                P1L(A,0); P1L(B,1); P1L(C,2); P1L(D,3);
                for (int kb = 0; kb <= 56; kb += 4) {
                    P1F(A); P1L(A, kb+4); P1F(B); P1L(B, kb+5);
                    P1F(C); P1L(C, kb+6); P1F(D); P1L(D, kb+7);
                }
                P1F(A); P1F(B); P1F(C); P1F(D);   // kq = 60..63
                sA[r1 * KP + e] = 2.f * sigm(a0) * x;
            }
        }
        __syncthreads();

        // ---- phase 2: hm[r][j] = 2*sig(xm[r] . R[:,j]) * h_prev[r][j] ----
        // 28 k-quads: 25 real (k=0..99) + 3 zero-weight (X reads hit
        // initialized hm region; products are 0).
        if (s == 0) {
            sA[r20 * KP + EE + j2] = 0.f;
            sA[r21 * KP + EE + j2] = 0.f;
        } else {
            float s0 = 0.f, s1 = 0.f;
            float4 rA, rB, rC, rD;
            float4 XA0, XA1, XB0, XB1, XC0, XC1, XD0, XD1;
            P2L(A,0); P2L(B,1); P2L(C,2); P2L(D,3);
            for (int kb = 0; kb <= 20; kb += 4) {     // kb = 0,4,8,12,16,20
                P2F(A); P2L(A, kb+4); P2F(B); P2L(B, kb+5);
                P2F(C); P2L(C, kb+6); P2F(D); P2L(D, kb+7);
            }
            P2F(A); P2F(B); P2F(C); P2F(D);           // kq = 24,25,26,27
            sA[r20 * KP + EE + j2] = 2.f * sigm(s0) * sH[r20 * HH + j2];
            sA[r21 * KP + EE + j2] = 2.f * sigm(s1) * sH[r21 * HH + j2];
        }
        __syncthreads();

        // ---- phase 3: G = [xm|hm] @ PW + bias  (4 cols x 2 rows / thread) --
        {
            float a00=bv.x,a01=bv.y,a02=bv.z,a03=bv.w;
            float a10=bv.x,a11=bv.y,a12=bv.z,a13=bv.w;
            float4 WA0,WA1,WA2,WA3,XA0,XA1, WB0,WB1,WB2,WB3,XB0,XB1;
            float4 WC0,WC1,WC2,WC3,XC0,XC1, WD0,WD1,WD2,WD3,XD0,XD1;
            P3L(A,0); P3L(B,4); P3L(C,8); P3L(D,12);
            for (int kb = 0; kb <= 344; kb += 16) {
                P3F(A); P3L(A, kb+16); P3F(B); P3L(B, kb+20);
                P3F(C); P3L(C, kb+24); P3F(D); P3L(D, kb+28);
            }
            P3F(A); P3F(B);                       // k = 360, 364 (C,D dups)
            *(float4*)(sG + (rg3 + 0) * G4 + n0) = make_float4(a00,a01,a02,a03);
            *(float4*)(sG + (rg3 + 1) * G4 + n0) = make_float4(a10,a11,a12,a13);
        }
        __syncthreads();

        // ---- phase 4: cell update; h -> sH (LDS) + nt-store to hout[t] ----
        {
            const float gi0 = sG[r4a*G4 + j4],       gi1 = sG[r4b*G4 + j4];
            const float gf0 = sG[r4a*G4 + 256 + j4], gf1 = sG[r4b*G4 + 256 + j4];
            const float gg0 = sG[r4a*G4 + 512 + j4], gg1 = sG[r4b*G4 + 512 + j4];
            const float go0 = sG[r4a*G4 + 768 + j4], go1 = sG[r4b*G4 + 768 + j4];
            c0 = sigm(gf0) * c0 + sigm(gi0) * tanhf(gg0);
            c1 = sigm(gf1) * c1 + sigm(gi1) * tanhf(gg1);
            const float h0 = sigm(go0) * tanhf(c0);
            const float h1 = sigm(go1) * tanhf(c1);
            sH[r4a * HH + j4] = h0;
            sH[r4b * HH + j4] = h1;
            __builtin_nontemporal_store(h0, &hout[((size_t)t * BB + b0 + r4a) * HH + j4]);
            __builtin_nontemporal_store(h1, &hout[((size_t)t * BB + b0 + r4b) * HH + j4]);
        }
        __syncthreads();
    }
}

// ---------------------------------------------------------------------------
// logits = [hf|hb] @ Wt^T + bt ; argmax (first index on ties) -> out[b][t]
// ---------------------------------------------------------------------------
__global__ __launch_bounds__(256) void logits_kernel(
    const float* __restrict__ hf, const float* __restrict__ hb,
    const float* __restrict__ Wt, const float* __restrict__ bt,
    int* __restrict__ out)
{
    __shared__ float sW[NTAG][2 * HH];
    __shared__ float sb[NTAG];
    const int tid = threadIdx.x;
    for (int i = tid; i < NTAG * 2 * HH; i += 256) (&sW[0][0])[i] = Wt[i];
    if (tid < NTAG) sb[tid] = bt[tid];
    __syncthreads();

    const int pos = blockIdx.x * 256 + tid;
    const int b  = pos & 511;
    const int t0 = pos >> 9;
    const int t1 = t0 + 64;

    float acc0[NTAG], acc1[NTAG];
    #pragma unroll
    for (int n = 0; n < NTAG; ++n) { acc0[n] = sb[n]; acc1[n] = sb[n]; }

    const float* f0 = hf + ((size_t)t0 * BB + b) * HH;
    const float* f1 = hf + ((size_t)t1 * BB + b) * HH;
    for (int k = 0; k < HH; k += 4) {
        const float4 a0 = *(const float4*)(f0 + k);
        const float4 a1 = *(const float4*)(f1 + k);
        #pragma unroll
        for (int n = 0; n < NTAG; ++n) {
            const float4 w = *(const float4*)&sW[n][k];
            acc0[n] += a0.x * w.x + a0.y * w.y + a0.z * w.z + a0.w * w.w;
            acc1[n] += a1.x * w.x + a1.y * w.y + a1.z * w.z + a1.w * w.w;
        }
    }
    const float* g0 = hb + ((size_t)t0 * BB + b) * HH;
    const float* g1 = hb + ((size_t)t1 * BB + b) * HH;
    for (int k = 0; k < HH; k += 4) {
        const float4 a0 = *(const float4*)(g0 + k);
        const float4 a1 = *(const float4*)(g1 + k);
        #pragma unroll
        for (int n = 0; n < NTAG; ++n) {
            const float4 w = *(const float4*)&sW[n][HH + k];
            acc0[n] += a0.x * w.x + a0.y * w.y + a0.z * w.z + a0.w * w.w;
            acc1[n] += a1.x * w.x + a1.y * w.y + a1.z * w.z + a1.w * w.w;
        }
    }

    float b0v = acc0[0]; int i0 = 0;
    float b1v = acc1[0]; int i1 = 0;
    #pragma unroll
    for (int n = 1; n < NTAG; ++n) {
        if (acc0[n] > b0v) { b0v = acc0[n]; i0 = n; }
        if (acc1[n] > b1v) { b1v = acc1[n]; i1 = n; }
    }
    out[b * TT + t0] = i0;
    out[b * TT + t1] = i1;
}

// ---------------------------------------------------------------------------
extern "C" void kernel_launch(void* const* d_in, const int* in_sizes, int n_in,
                              void* d_out, int out_size, void* d_ws, size_t ws_size,
                              hipStream_t stream)
{
    (void)in_sizes; (void)n_in; (void)out_size; (void)ws_size;

    const int*   words = (const int*)  d_in[0];
    const float* embd  = (const float*)d_in[5];
    const float* Wih_f = (const float*)d_in[6];
    const float* Whh_f = (const float*)d_in[7];
    const float* bih_f = (const float*)d_in[8];
    const float* bhh_f = (const float*)d_in[9];
    const float* Q_f   = (const float*)d_in[10];
    const float* R_f   = (const float*)d_in[11];
    const float* Wih_b = (const float*)d_in[12];
    const float* Whh_b = (const float*)d_in[13];
    const float* bih_b = (const float*)d_in[14];
    const float* bhh_b = (const float*)d_in[15];
    const float* Q_b   = (const float*)d_in[16];
    const float* R_b   = (const float*)d_in[17];
    const float* Wt    = (const float*)d_in[18];
    const float* bt    = (const float*)d_in[19];
    int* out = (int*)d_out;

    // workspace layout (floats), total ~138 MB
    float* ws   = (float*)d_ws;
    float* PW_f = ws;                         // 376832
    float* QP_f = PW_f + PWPSZ;               // 25600
    float* RP_f = QP_f + QPSZ;                // 28672
    float* bP_f = RP_f + RPSZ;                // 1024
    float* PW_b = bP_f + G4;
    float* QP_b = PW_b + PWPSZ;
    float* RP_b = QP_b + QPSZ;
    float* bP_b = RP_b + RPSZ;
    float* hf   = bP_b + G4;                  // 16777216
    float* hb   = hf + (size_t)TT * BB * HH;  // 16777216

    const int prep_grid = (PWPSZ + QPSZ + RPSZ + G4 + 255) / 256;
    prep6<<<prep_grid, 256, 0, stream>>>(Wih_f, Whh_f, bih_f, bhh_f, Q_f, R_f,
                                         PW_f, QP_f, RP_f, bP_f);
    prep6<<<prep_grid, 256, 0, stream>>>(Wih_b, Whh_b, bih_b, bhh_b, Q_b, R_b,
                                         PW_b, QP_b, RP_b, bP_b);
    lstm6<<<256, 512, 0, stream>>>(words, embd, QP_f, RP_f, PW_f, bP_f,
                                   QP_b, RP_b, PW_b, bP_b, hf, hb);
    logits_kernel<<<128, 256, 0, stream>>>(hf, hb, Wt, bt, out);
}